// Round 13
// baseline (238.443 us; speedup 1.0000x reference)
//
#include <hip/hip_runtime.h>
#include <hip/hip_bf16.h>
#include <cstdint>
#include <cstddef>

#define DEV __device__ __forceinline__

typedef __attribute__((ext_vector_type(8))) short  s8v;    // 8 bf16 (4 VGPR)
typedef __attribute__((ext_vector_type(4))) float  f4v;    // MFMA acc / 16B f32 load
typedef __attribute__((ext_vector_type(4))) uint32_t u4v;  // 16B packed store

// ---------- bf16 helpers ----------
DEV unsigned short f2bf(float x) {                 // RNE bithack (host-independent path)
  union { float f; uint32_t u; } v; v.f = x;
  uint32_t u = v.u + 0x7FFFu + ((v.u >> 16) & 1u);
  return (unsigned short)(u >> 16);
}
// HW packed convert: 2 f32 -> u32 of 2 bf16 (RNE, identical to f2bf)
DEV uint32_t cvtpk2(float lo, float hi) {
  uint32_t r;
  asm("v_cvt_pk_bf16_f32 %0, %1, %2" : "=v"(r) : "v"(lo), "v"(hi));
  return r;
}
DEV unsigned short f2bf_fast(float x) { return (unsigned short)cvtpk2(x, 0.f); }
DEV float bf2f(unsigned short b) {
  union { uint32_t u; float f; } v; v.u = ((uint32_t)b) << 16;
  return v.f;
}

// ---------- async global->LDS 16B (dest = wave-uniform base + lane*16) ----------
DEV void async_copy16(void* lds, const void* g) {
  typedef __attribute__((address_space(3))) uint32_t lds_t;
  typedef const __attribute__((address_space(1))) uint32_t g_t;
  __builtin_amdgcn_global_load_lds((g_t*)g, (lds_t*)lds, 16, 0, 0);
}

#define WAITV4()    asm volatile("s_waitcnt vmcnt(4)" ::: "memory")
#define WAITV0()    asm volatile("s_waitcnt vmcnt(0)" ::: "memory")
#define MEMFENCE()  asm volatile("" ::: "memory")

constexpr int Bc = 32, Oc = 256, Tc = 1024;
constexpr int BM = 128, BN = 128, BK = 64;         // 128^2 kernel tile
constexpr int CSR_CAP = 46;   // max degree per (b,o); P(exceed) ~ 1e-19

// bijective XCD chunk swizzle + n-inner decomposition.
DEV void swz_mn(int nyb, int* mb, int* nb) {
  const int nwg = gridDim.x * gridDim.y;            // multiple of 8 for all uses
  const int w   = blockIdx.x + blockIdx.y * gridDim.x;
  const int cpx = nwg >> 3;
  const int s   = (w & 7) * cpx + (w >> 3);
  *mb = s / nyb;
  *nb = s % nyb;
}

// ---------------------------------------------------------------------------
// prologue_k: ALL independent prologue work in ONE launch (was 7 dispatches;
// measured ~30us saved in round 10).  Block-range role dispatch:
//   [0,8192)      cvt pred  f32->bf16 (8 elem/thread)
//   [8192,10240)  cvt obj   f32->bf16
//   [10240,11008) tcvt W1a | [11008,11776) tcvt W1b
//   [11776,12032) tcvt W2a | [12032,12288) tcvt W2b
//   [12288,12416) detect: mask-dtype sniff (flag pre-zeroed by memset)
// ---------------------------------------------------------------------------
__global__ __launch_bounds__(256)
void prologue_k(const float* __restrict__ pred, const float* __restrict__ obj,
                const float* __restrict__ W1a, const float* __restrict__ W1b,
                const float* __restrict__ W2a, const float* __restrict__ W2b,
                unsigned short* __restrict__ predb, unsigned short* __restrict__ objb,
                unsigned short* __restrict__ W1at, unsigned short* __restrict__ W1bt,
                unsigned short* __restrict__ W2at, unsigned short* __restrict__ W2bt,
                const unsigned char* __restrict__ maskb, int* __restrict__ flag)
{
  __shared__ float tile[32][33];
  const int b = blockIdx.x;
  const int tid = threadIdx.x;

  if (b < 10240) {                                  // bulk f32->bf16 convert
    const float* in = (b < 8192) ? pred : obj;
    unsigned short* outp = (b < 8192) ? predb : objb;
    const int i = ((b < 8192) ? b : b - 8192) * 256 + tid;
    const f4v v0 = *(const f4v*)(in + (size_t)i * 8);
    const f4v v1 = *(const f4v*)(in + (size_t)i * 8 + 4);
    u4v pk;
    pk.x = cvtpk2(v0.x, v0.y);
    pk.y = cvtpk2(v0.z, v0.w);
    pk.z = cvtpk2(v1.x, v1.y);
    pk.w = cvtpk2(v1.z, v1.w);
    *(u4v*)(outp + (size_t)i * 8) = pk;
  } else if (b < 12288) {                           // weight transpose+convert
    const float* W; unsigned short* Wt; int K, N, kb, nb;
    if (b < 11008)      { W = W1a; Wt = W1at; K = 1536; N = 512;
                          const int r = b - 10240; kb = r % 48; nb = r / 48; }
    else if (b < 11776) { W = W1b; Wt = W1bt; K = 512;  N = 1536;
                          const int r = b - 11008; kb = r % 16; nb = r / 16; }
    else if (b < 12032) { W = W2a; Wt = W2at; K = 512;  N = 512;
                          const int r = b - 11776; kb = r % 16; nb = r / 16; }
    else                { W = W2b; Wt = W2bt; K = 512;  N = 512;
                          const int r = b - 12032; kb = r % 16; nb = r / 16; }
    const int k0 = kb * 32, n0 = nb * 32;
    const int tx = tid & 31, ty = tid >> 5;
    #pragma unroll
    for (int i = 0; i < 32; i += 8)
      tile[ty + i][tx] = W[(size_t)(k0 + ty + i) * N + (n0 + tx)];
    __syncthreads();
    #pragma unroll
    for (int i = 0; i < 32; i += 8)
      Wt[(size_t)(n0 + ty + i) * K + (k0 + tx)] = f2bf(tile[tx][ty + i]);
  } else {                                          // detect (parallel)
    const int i = (b - 12288) * 256 + tid;          // covers 32768 bytes
    const int local = ((i & 3) && maskb[i]) ? 1 : 0;
    const unsigned long long bal = __ballot(local);
    if (bal != 0 && (tid & 63) == 0) atomicOr(flag, 1);
  }
}

// ---------------------------------------------------------------------------
// 256x256 8-wave phase-interleaved K-loop with fragment-register reuse.
// (GEMM1 only — measured best: 68.5us vs 77us factored, vs ~87us 128^2.)
// ---------------------------------------------------------------------------
#define READ_A(QM, DST) do {                                                    \
    _Pragma("unroll")                                                           \
    for (int i = 0; i < 4; ++i) {                                               \
      const int row = wm * 128 + ((QM) * 4 + i) * 16 + (lane & 15);             \
      _Pragma("unroll")                                                         \
      for (int kk = 0; kk < 2; ++kk) {                                          \
        const int c = kk * 4 + (lane >> 4);                                     \
        DST[i][kk] = *(const s8v*)(Ab_ + row * 128 + ((c ^ (row & 7)) << 4));   \
      }                                                                         \
    }                                                                           \
  } while (0)

#define READ_B(QN, DST) do {                                                    \
    _Pragma("unroll")                                                           \
    for (int j = 0; j < 2; ++j) {                                               \
      const int row = wn * 64 + ((QN) * 2 + j) * 16 + (lane & 15);              \
      _Pragma("unroll")                                                         \
      for (int kk = 0; kk < 2; ++kk) {                                          \
        const int c = kk * 4 + (lane >> 4);                                     \
        DST[j][kk] = *(const s8v*)(Bb_ + row * 128 + ((c ^ (row & 7)) << 4));   \
      }                                                                         \
    }                                                                           \
  } while (0)

#define SYNC_MFMA(QM, QN, AF, BF) do {                                          \
    MEMFENCE();                                                                 \
    __builtin_amdgcn_s_barrier();                                               \
    asm volatile("s_waitcnt lgkmcnt(0)" ::: "memory");                          \
    __builtin_amdgcn_sched_barrier(0);                                          \
    __builtin_amdgcn_s_setprio(1);                                              \
    _Pragma("unroll")                                                           \
    for (int i = 0; i < 4; ++i)                                                 \
      _Pragma("unroll")                                                         \
      for (int j = 0; j < 2; ++j)                                               \
        _Pragma("unroll")                                                       \
        for (int kk = 0; kk < 2; ++kk)                                          \
          acc[(QM) * 4 + i][(QN) * 2 + j] =                                     \
            __builtin_amdgcn_mfma_f32_16x16x32_bf16(                            \
              AF[i][kk], BF[j][kk], acc[(QM) * 4 + i][(QN) * 2 + j], 0, 0, 0);  \
    __builtin_amdgcn_s_setprio(0);                                              \
  } while (0)

#define ENDPHASE() do { MEMFENCE(); __builtin_amdgcn_s_barrier(); } while (0)

#define KTILE_BODY() do {                                                       \
    const int par = t & 1, px = par ^ 1;                                        \
    const char* Ab_ = smem + par * 65536;                                       \
    const char* Bb_ = Ab_ + 32768;                                              \
    const bool s1 = (t + 1 < nk), s2 = (t + 2 < nk);                            \
    /* P0 */                                                                    \
    READ_A(0, af); READ_B(0, bf0);                                              \
    if (s1) stageA(px, 1, t + 1);                                               \
    SYNC_MFMA(0, 0, af, bf0);                                                   \
    ENDPHASE();                                                                 \
    /* P1 */                                                                    \
    READ_B(1, bf1);                                                             \
    if (s1) stageB(px, 1, t + 1);                                               \
    SYNC_MFMA(0, 1, af, bf1);                                                   \
    ENDPHASE();                                                                 \
    /* P2 */                                                                    \
    READ_A(1, af);                                                              \
    if (s2) stageA(par, 0, t + 2);                                              \
    SYNC_MFMA(1, 1, af, bf1);                                                   \
    ENDPHASE();                                                                 \
    /* P3 */                                                                    \
    if (s2) stageB(par, 0, t + 2);                                              \
    SYNC_MFMA(1, 0, af, bf0);                                                   \
    if (s2) { WAITV4(); } else if (s1) { WAITV0(); }                            \
    ENDPHASE();                                                                 \
  } while (0)

// ---------------------------------------------------------------------------
// Gathered-A 256^2 GEMM (GEMM1): A row m = [objb[s(m)], predb[m], objb[o(m)]]
// M=32768 N=512 K=1536.
// ---------------------------------------------------------------------------
__global__ __launch_bounds__(512, 2)
void gemm8g_k(const unsigned short* __restrict__ objb,
              const unsigned short* __restrict__ predb,
              const int* __restrict__ edges,
              const unsigned short* __restrict__ Bt,   // (512,1536) bf16
              const float* __restrict__ bias,
              unsigned short* __restrict__ outp)       // (32768,512) bf16
{
  __shared__ __align__(16) char smem[131072];

  const int tid = threadIdx.x, lane = tid & 63, wave = tid >> 6;
  const int wm = wave >> 2, wn = wave & 3;
  int mb, nb; swz_mn(gridDim.y, &mb, &nb);
  const int m0 = mb * 256, n0 = nb * 256;
  const int rl  = tid >> 3;
  const int cs8 = ((lane & 7) ^ (lane >> 3)) * 8;
  const int rB0 = (rl >> 5) * 64 + (rl & 31);

  // 12 per-thread gathered byte offsets; c2 = s*2+qm -> row = s*128+qm*64+rl
  uint32_t offS[4], offP[4], offO[4];
  #pragma unroll
  for (int c2 = 0; c2 < 4; ++c2) {
    const int r = (c2 >> 1) * 128 + (c2 & 1) * 64 + rl;
    const int m = m0 + r;
    const int ob = (m >> 10) * Oc;
    offS[c2] = (uint32_t)((ob + edges[2 * m])     * 1024 + cs8 * 2);
    offO[c2] = (uint32_t)((ob + edges[2 * m + 1]) * 1024 + cs8 * 2);
    offP[c2] = (uint32_t)(m * 1024 + cs8 * 2);
  }
  const unsigned short* srcB = Bt + (size_t)(n0 + rB0) * 1536 + cs8;

  auto stageA = [&](int p, int qm, int kt) {
    const int reg = kt >> 3;
    const uint32_t koff = (uint32_t)(kt & 7) * 128u;
    #pragma unroll
    for (int s = 0; s < 2; ++s) {
      const int c2 = s * 2 + qm;
      const char* src;
      if (reg == 0)      src = (const char*)objb  + offS[c2] + koff;
      else if (reg == 1) src = (const char*)predb + offP[c2] + koff;
      else               src = (const char*)objb  + offO[c2] + koff;
      async_copy16(smem + p * 65536 + ((s * 128 + qm * 64 + wave * 8) << 7), src);
    }
  };
  auto stageB = [&](int p, int qn, int kt) {
    #pragma unroll
    for (int s = 0; s < 2; ++s)
      async_copy16(smem + p * 65536 + 32768 +
                     ((s * 128 + qn * 32 + (wave >> 2) * 64 + (wave & 3) * 8) << 7),
                   srcB + (size_t)(s * 128 + qn * 32) * 1536 + kt * 64);
  };

  f4v acc[8][4] = {};
  s8v af[4][2], bf0[2][2], bf1[2][2];
  constexpr int nk = 24;

  stageA(0, 0, 0); stageB(0, 0, 0); stageA(0, 1, 0); stageB(0, 1, 0);
  stageA(1, 0, 1); stageB(1, 0, 1);
  WAITV4();
  MEMFENCE();
  __builtin_amdgcn_s_barrier();

  for (int t = 0; t < nk; ++t) KTILE_BODY();

  const int cn = lane & 15, rq4 = (lane >> 4) * 4;
  #pragma unroll
  for (int f = 0; f < 8; ++f) {
    const int gr0 = m0 + wm * 128 + f * 16 + rq4;
    #pragma unroll
    for (int g = 0; g < 4; ++g) {
      const int gc = n0 + wn * 64 + g * 16 + cn;
      const float bv = bias[gc];
      #pragma unroll
      for (int r = 0; r < 4; ++r) {
        float val = acc[f][g][r] + bv;
        val = val > 0.f ? val : 0.f;
        outp[(size_t)(gr0 + r) * 512 + gc] = f2bf_fast(val);
      }
    }
  }
}

// ---------------------------------------------------------------------------
// Generic 128x128 bf16 GEMM (single-buffer).
// EPI: 0 = relu->bf16 (stride N); 2 = relu->f32
// ---------------------------------------------------------------------------
template<int EPI>
__global__ __launch_bounds__(256)
void gemm_k(const unsigned short* __restrict__ Abf,
            const unsigned short* __restrict__ Bt,
            const float* __restrict__ bias,
            unsigned short* __restrict__ out_bf,
            float* __restrict__ out_f32,
            int M, int N, int K)
{
  __shared__ __align__(16) char smem[BM * BK * 2 + BN * BK * 2];
  char* As = smem;
  char* Bs = smem + BM * BK * 2;

  const int tid  = threadIdx.x;
  const int lane = tid & 63;
  const int wave = tid >> 6;
  const int wm = wave >> 1, wn = wave & 1;
  int mb, nb; swz_mn(gridDim.y, &mb, &nb);
  const int m0 = mb * BM;
  const int n0 = nb * BN;

  f4v acc[4][4] = {};

  for (int k0 = 0; k0 < K; k0 += BK) {
    {
      const int r8 = lane >> 3;
      const int cs = (lane & 7) ^ r8;
      const unsigned short* src = Bt + (size_t)(n0 + wave * 32 + r8) * K + k0 + cs * 8;
      #pragma unroll
      for (int i = 0; i < 4; ++i)
        async_copy16(Bs + (wave * 32 + i * 8) * 128, src + (size_t)i * 8 * K);
      const unsigned short* srca = Abf + (size_t)(m0 + wave * 32 + r8) * K + k0 + cs * 8;
      #pragma unroll
      for (int i = 0; i < 4; ++i)
        async_copy16(As + (wave * 32 + i * 8) * 128, srca + (size_t)i * 8 * K);
    }
    __syncthreads();

    #pragma unroll
    for (int kk = 0; kk < 2; ++kk) {
      s8v af[4], bfv[4];
      #pragma unroll
      for (int i = 0; i < 4; ++i) {
        const int row = wm * 64 + i * 16 + (lane & 15);
        const int c = kk * 4 + (lane >> 4);
        af[i] = *(const s8v*)(As + row * 128 + ((c ^ (row & 7)) << 4));
      }
      #pragma unroll
      for (int j = 0; j < 4; ++j) {
        const int row = wn * 64 + j * 16 + (lane & 15);
        const int c = kk * 4 + (lane >> 4);
        bfv[j] = *(const s8v*)(Bs + row * 128 + ((c ^ (row & 7)) << 4));
      }
      #pragma unroll
      for (int i = 0; i < 4; ++i)
        #pragma unroll
        for (int j = 0; j < 4; ++j)
          acc[i][j] = __builtin_amdgcn_mfma_f32_16x16x32_bf16(af[i], bfv[j], acc[i][j], 0, 0, 0);
    }
    __syncthreads();
  }

  const int cn = lane & 15, rq4 = (lane >> 4) * 4;
  #pragma unroll
  for (int i = 0; i < 4; ++i) {
    const int gr0 = m0 + wm * 64 + i * 16 + rq4;
    #pragma unroll
    for (int j = 0; j < 4; ++j) {
      const int gc = n0 + wn * 64 + j * 16 + cn;
      const float bv = bias[gc];
      #pragma unroll
      for (int r = 0; r < 4; ++r) {
        float val = acc[i][j][r] + bv;
        val = val > 0.f ? val : 0.f;
        const int gr = gr0 + r;
        if (EPI == 0) out_bf[(size_t)gr * N + gc] = f2bf_fast(val);
        else          out_f32[(size_t)gr * N + gc] = val;
      }
    }
  }
}

// ---------------------------------------------------------------------------
// GEMM2p PERSISTENT (2 m-tiles/block): h @ W1b_p -> relu*conf -> new_p (f32).
// Grid (64,8)=512 blocks, 2 blocks/CU co-resident; per-block ramp amortized
// over 16 K-steps instead of 8. Inner structure identical to gemm_k.
// ---------------------------------------------------------------------------
__global__ __launch_bounds__(256)
void gemm2p_k(const unsigned short* __restrict__ h,
              const unsigned short* __restrict__ Bt,    // W1bt + 512*512
              const float* __restrict__ bias,           // b1b + 512
              const float* __restrict__ conf,
              float* __restrict__ out_p)
{
  __shared__ __align__(16) char smem[BM * BK * 2 + BN * BK * 2];
  char* As = smem;
  char* Bs = smem + BM * BK * 2;

  const int tid  = threadIdx.x;
  const int lane = tid & 63;
  const int wave = tid >> 6;
  const int wm = wave >> 1, wn = wave & 1;
  int mbg, nb; swz_mn(4, &mbg, &nb);        // 128 m-groups x 4 n-tiles
  const int n0 = nb * BN;
  const int r8 = lane >> 3;
  const int cs = (lane & 7) ^ r8;
  const unsigned short* srcb = Bt + (size_t)(n0 + wave * 32 + r8) * 512 + cs * 8;
  const int cn = lane & 15, rq4 = (lane >> 4) * 4;

  #pragma unroll 1
  for (int mt = 0; mt < 2; ++mt) {
    const int m0 = (mbg * 2 + mt) * BM;
    const unsigned short* srca = h + (size_t)(m0 + wave * 32 + r8) * 512 + cs * 8;
    f4v acc[4][4] = {};

    for (int k0 = 0; k0 < 512; k0 += BK) {
      #pragma unroll
      for (int i = 0; i < 4; ++i)
        async_copy16(Bs + (wave * 32 + i * 8) * 128, srcb + k0 + (size_t)(i * 8) * 512);
      #pragma unroll
      for (int i = 0; i < 4; ++i)
        async_copy16(As + (wave * 32 + i * 8) * 128, srca + k0 + (size_t)(i * 8) * 512);
      __syncthreads();

      #pragma unroll
      for (int kk = 0; kk < 2; ++kk) {
        s8v af[4], bfv[4];
        #pragma unroll
        for (int i = 0; i < 4; ++i) {
          const int row = wm * 64 + i * 16 + (lane & 15);
          const int c = kk * 4 + (lane >> 4);
          af[i] = *(const s8v*)(As + row * 128 + ((c ^ (row & 7)) << 4));
        }
        #pragma unroll
        for (int j = 0; j < 4; ++j) {
          const int row = wn * 64 + j * 16 + (lane & 15);
          const int c = kk * 4 + (lane >> 4);
          bfv[j] = *(const s8v*)(Bs + row * 128 + ((c ^ (row & 7)) << 4));
        }
        #pragma unroll
        for (int i = 0; i < 4; ++i)
          #pragma unroll
          for (int j = 0; j < 4; ++j)
            acc[i][j] = __builtin_amdgcn_mfma_f32_16x16x32_bf16(af[i], bfv[j], acc[i][j], 0, 0, 0);
      }
      __syncthreads();
    }

    #pragma unroll
    for (int i = 0; i < 4; ++i) {
      const int gr0 = m0 + wm * 64 + i * 16 + rq4;
      #pragma unroll
      for (int j = 0; j < 4; ++j) {
        const int lc = wn * 64 + j * 16 + cn;
        const float bv = bias[n0 + lc];
        #pragma unroll
        for (int r = 0; r < 4; ++r) {
          const int gr = gr0 + r;
          float val = acc[i][j][r] + bv;
          val = val > 0.f ? val : 0.f;
          out_p[(size_t)gr * 512 + n0 + lc] = val * conf[gr];
        }
      }
    }
  }
}

// ---------------------------------------------------------------------------
// GEMM2so PERSISTENT (2 m-tiles/block) over COMPACTED masked rows.
// Active-count-aware bijective XCD swizzle over mgs*8 groups (256 rows each).
// ---------------------------------------------------------------------------
__global__ __launch_bounds__(256)
void gemm2so_k(const unsigned short* __restrict__ h,
               const int* __restrict__ torig,
               const float* __restrict__ confc,
               const unsigned short* __restrict__ W1bt,   // (1536,512) bf16
               const float* __restrict__ b1b,
               const int* __restrict__ minfo,             // [0]=M', [1]=Mpad
               unsigned short* __restrict__ news_c,
               unsigned short* __restrict__ newo_c)
{
  const int Mp   = minfo[1];
  const int mgs  = (Mp + 255) >> 8;              // groups of 2 tiles (256 rows)
  const int nact = mgs * 8;                      // multiple of 8
  const int w    = blockIdx.x + blockIdx.y * gridDim.x;
  if (w >= nact) return;                         // uniform exit, pre-barrier
  const int cpx = nact >> 3;
  const int s   = (w & 7) * cpx + (w >> 3);      // bijective over [0,nact)
  const int mg  = s >> 3, nb = s & 7;            // n-inner
  const int Mr  = minfo[0];                      // > 0 here

  __shared__ __align__(16) char smem[BM * BK * 2 + BN * BK * 2];
  char* As = smem;
  char* Bs = smem + BM * BK * 2;

  const int tid  = threadIdx.x;
  const int lane = tid & 63;
  const int wave = tid >> 6;
  const int wm = wave >> 1, wn = wave & 1;
  const int n0 = nb * BN;                        // 0..1023 logical so-col
  const int r8 = lane >> 3;
  const int cs8 = ((lane & 7) ^ r8) * 8;
  const int nrow0 = (nb < 4) ? n0 : n0 + 512;    // skip p-rows of W1bt
  const unsigned short* bsrc = W1bt + (size_t)(nrow0 + wave * 32 + r8) * 512 + cs8;
  const float* bb = b1b + ((nb < 4) ? n0 : 512 + n0);   // s:0..511, o:1024..1535
  unsigned short* outp = (nb < 4) ? news_c : newo_c;
  const int c0 = (nb & 3) * 128;
  const int cn = lane & 15, rq4 = (lane >> 4) * 4;

  #pragma unroll 1
  for (int mt = 0; mt < 2; ++mt) {
    const int m0 = (mg * 2 + mt) * BM;
    if (m0 >= Mp) break;                         // block-uniform tail skip

    // gathered per-lane A row pointers (4 rows: wave*32 + i*8 + r8)
    const unsigned short* aP[4];
    #pragma unroll
    for (int i = 0; i < 4; ++i) {
      int m = m0 + wave * 32 + i * 8 + r8;
      m = m < Mr ? m : Mr - 1;
      aP[i] = h + (size_t)torig[m] * 512 + cs8;
    }

    f4v acc[4][4] = {};

    for (int kt = 0; kt < 8; ++kt) {
      const int kin = kt * 64;
      #pragma unroll
      for (int i = 0; i < 4; ++i)
        async_copy16(Bs + (wave * 32 + i * 8) * 128, bsrc + (size_t)(i * 8) * 512 + kin);
      #pragma unroll
      for (int i = 0; i < 4; ++i)
        async_copy16(As + (wave * 32 + i * 8) * 128, aP[i] + kin);
      __syncthreads();

      #pragma unroll
      for (int kk = 0; kk < 2; ++kk) {
        s8v af[4], bfv[4];
        #pragma unroll
        for (int i = 0; i < 4; ++i) {
          const int row = wm * 64 + i * 16 + (lane & 15);
          const int c = kk * 4 + (lane >> 4);
          af[i] = *(const s8v*)(As + row * 128 + ((c ^ (row & 7)) << 4));
        }
        #pragma unroll
        for (int j = 0; j < 4; ++j) {
          const int row = wn * 64 + j * 16 + (lane & 15);
          const int c = kk * 4 + (lane >> 4);
          bfv[j] = *(const s8v*)(Bs + row * 128 + ((c ^ (row & 7)) << 4));
        }
        #pragma unroll
        for (int i = 0; i < 4; ++i)
          #pragma unroll
          for (int j = 0; j < 4; ++j)
            acc[i][j] = __builtin_amdgcn_mfma_f32_16x16x32_bf16(af[i], bfv[j], acc[i][j], 0, 0, 0);
      }
      __syncthreads();
    }

    #pragma unroll
    for (int i = 0; i < 4; ++i) {
      const int gr0 = m0 + wm * 64 + i * 16 + rq4;
      #pragma unroll
      for (int j = 0; j < 4; ++j) {
        const int lc = wn * 64 + j * 16 + cn;
        const float bv = bb[lc];
        #pragma unroll
        for (int r = 0; r < 4; ++r) {
          const int gr = gr0 + r;
          float val = acc[i][j][r] + bv;
          val = val > 0.f ? val : 0.f;
          val *= confc[gr < Mr ? gr : 0];
          if (gr < Mr) outp[(size_t)gr * 512 + c0 + lc] = f2bf_fast(val);
        }
      }
    }
  }
}

// ---------------------------------------------------------------------------
// prep (+ fused scan1): 32 blocks x 1024. Computes conf/se/oe AND per-block
// masked-count bsum (the ballot is needed anyway).
// ---------------------------------------------------------------------------
__global__ __launch_bounds__(1024)
void prep_k(const int* __restrict__ tt, const int* __restrict__ pid,
            const float* __restrict__ ptw, const int* __restrict__ edges,
            const void* __restrict__ mask, const int* __restrict__ u8flag,
            float* __restrict__ conf, int* __restrict__ se,
            int* __restrict__ oe, int* __restrict__ bsum)
{
  const int m = blockIdx.x * 1024 + threadIdx.x;
  const int t = tt[m];
  float c = 0.f;
  if (t == 0) c = 1.f;
  else if (t == 1) c = 1.f / (1.f + expf(-ptw[pid[m]]));
  conf[m] = c;
  bool mk;
  if (*u8flag) mk = ((const unsigned char*)mask)[m] != 0;
  else         mk = ((const int*)mask)[m] != 0;
  se[m] = mk ? edges[2 * m]     : -1;
  oe[m] = mk ? edges[2 * m + 1] : -1;

  const unsigned long long bal = __ballot(mk);
  __shared__ int wc[16];
  if ((threadIdx.x & 63) == 0) wc[threadIdx.x >> 6] = (int)__popcll(bal);
  __syncthreads();
  if (threadIdx.x == 0) {
    int ssum = 0;
    #pragma unroll
    for (int i = 0; i < 16; ++i) ssum += wc[i];
    bsum[blockIdx.x] = ssum;
  }
}

__global__ void scan2_k(const int* __restrict__ bsum, int* __restrict__ boff,
                        int* __restrict__ minfo)
{
  if (threadIdx.x == 0) {
    int s = 0;
    for (int i = 0; i < 32; ++i) { boff[i] = s; s += bsum[i]; }
    minfo[0] = s;
    minfo[1] = (s + 127) & ~127;
  }
}

__global__ __launch_bounds__(1024)
void scan3_k(const int* __restrict__ se, const int* __restrict__ boff,
             const float* __restrict__ conf,
             int* __restrict__ torig, int* __restrict__ cmap,
             float* __restrict__ confc)
{
  const int m = blockIdx.x * 1024 + threadIdx.x;
  const int lane = threadIdx.x & 63, w = threadIdx.x >> 6;
  const bool mv = se[m] >= 0;
  const unsigned long long bal = __ballot(mv);
  __shared__ int wc[16];
  if (lane == 0) wc[w] = (int)__popcll(bal);
  __syncthreads();
  int woff = 0;
  for (int i = 0; i < w; ++i) woff += wc[i];
  if (mv) {
    const int c = boff[blockIdx.x] + woff +
                  (int)__popcll(bal & ((1ull << lane) - 1ull));
    torig[c] = m;
    cmap[m]  = c;
    confc[c] = conf[m];
  }
}

// ---------------------------------------------------------------------------
// Wave-parallel CSR build: one wave per (b,o). Deterministic via ballot rank.
// ---------------------------------------------------------------------------
__global__ __launch_bounds__(256)
void csr2_k(const int* __restrict__ se, const int* __restrict__ oe,
            int* __restrict__ deg, int* __restrict__ slot)
{
  const int wid  = blockIdx.x * 4 + (threadIdx.x >> 6);  // (b<<8)|u
  const int b    = wid >> 8;
  const int u    = wid & 255;
  const int lane = threadIdx.x & 63;
  const int mb   = b * Tc;
  int* sl = slot + (size_t)wid * CSR_CAP;
  const unsigned long long lt = (1ull << lane) - 1ull;
  int cnt = 0;
  #pragma unroll 4
  for (int c = 0; c < 16; ++c) {
    const int t = c * 64 + lane;
    const int s = se[mb + t];
    const int o = oe[mb + t];
    const unsigned long long ms = __ballot(s == u);
    const unsigned long long mo = __ballot(o == u);
    if (s == u) {
      const int pos = cnt + (int)__popcll(ms & lt);
      if (pos < CSR_CAP) sl[pos] = 2 * t;
    }
    cnt += (int)__popcll(ms);
    if (o == u) {
      const int pos = cnt + (int)__popcll(mo & lt);
      if (pos < CSR_CAP) sl[pos] = 2 * t + 1;
    }
    cnt += (int)__popcll(mo);
  }
  if (lane == 0) deg[wid] = cnt < CSR_CAP ? cnt : CSR_CAP;
}

// ---------------------------------------------------------------------------
// CSR pool over COMPACTED rows: row index = cmap[b*Tc + t].
// ---------------------------------------------------------------------------
__global__ __launch_bounds__(256)
void pool2_k(const unsigned short* __restrict__ S, const unsigned short* __restrict__ Ov,
             const int* __restrict__ deg, const int* __restrict__ slot,
             const float* __restrict__ conf, const int* __restrict__ cmap,
             unsigned short* __restrict__ pooled)
{
  const int bo = blockIdx.x;            // b*256 + o
  const int b  = bo >> 8;
  const int u  = threadIdx.x;
  const int d  = deg[bo];
  const int* sl = slot + (size_t)bo * CSR_CAP;
  float a0 = 0.f, a1 = 0.f, w = 0.f;
  for (int i = 0; i < d; ++i) {
    const int e = sl[i];                // uniform load
    const int t = e >> 1;
    const int c = cmap[b * Tc + t];     // valid: slots contain masked t only
    const unsigned short* row = ((e & 1) ? Ov : S) + (size_t)c * 512;
    const uint32_t pr = *(const uint32_t*)(row + 2 * u);
    a0 += bf2f((unsigned short)pr);
    a1 += bf2f((unsigned short)(pr >> 16));
    w  += conf[b * Tc + t];
  }
  const float denom = (w > 0.f) ? w : 1.f;
  const size_t ob = (size_t)bo * 512;
  *(uint32_t*)(pooled + ob + 2 * u) = cvtpk2(a0 / denom, a1 / denom);
}

// ---------------------------------------------------------------------------
extern "C" void kernel_launch(void* const* d_in, const int* in_sizes, int n_in,
                              void* d_out, int out_size, void* d_ws, size_t ws_size,
                              hipStream_t stream)
{
  const float* obj  = (const float*)d_in[0];
  const float* pred = (const float*)d_in[1];
  const float* W1a  = (const float*)d_in[2];
  const float* b1a  = (const float*)d_in[3];
  const float* W1b  = (const float*)d_in[4];
  const float* b1b  = (const float*)d_in[5];
  const float* W2a  = (const float*)d_in[6];
  const float* b2a  = (const float*)d_in[7];
  const float* W2b  = (const float*)d_in[8];
  const float* b2b  = (const float*)d_in[9];
  const float* ptw  = (const float*)d_in[10];
  const int*   edges = (const int*)d_in[11];
  const void*  mask  = d_in[12];
  const int*   tt    = (const int*)d_in[13];
  const int*   pid   = (const int*)d_in[14];
  float* out = (float*)d_out;

  char* ws = (char*)d_ws;
  // [0, 4194304): transposed bf16 weights.
  // W1at [0, 1572864) is DEAD after gemm1 -> reused for CSR deg+slot.
  unsigned short* W1at = (unsigned short*)(ws + 0);          // 512x1536
  unsigned short* W1bt = (unsigned short*)(ws + 1572864);    // 1536x512
  unsigned short* W2at = (unsigned short*)(ws + 3145728);    // 512x512
  unsigned short* W2bt = (unsigned short*)(ws + 3670016);    // 512x512
  int* deg  = (int*)(ws + 0);                                // 8192 ints
  int* slot = (int*)(ws + 32768);                            // 8192*46 ints
  unsigned short* h    = (unsigned short*)(ws + 4194304);    // 32768x512 bf16, 32MB
  unsigned short* pooled = h;                                // 8192x512 (post-GEMM2)
  unsigned short* h2   = (unsigned short*)(ws + 12582912);   // 8192x512 bf16 (GEMM3 out)
  unsigned short* news = (unsigned short*)(ws + 37748736);   // 32768x512 bf16 (compacted)
  unsigned short* newo = (unsigned short*)(ws + 71303168);   // 32768x512 bf16 (compacted)
  unsigned short* objb = news;                               // 32x256x512 (pre-GEMM1)
  unsigned short* predb = (unsigned short*)(ws + 46137344);  // 32x1024x512
  float* conf = (float*)(ws + 104857600);
  int*   se   = (int*)(ws + 104988672);
  int*   oe   = (int*)(ws + 105119744);
  int* u8flag = (int*)(ws + 105250816);

  // Compaction scratch lives in d_out's new_obj region [0, 400KB):
  // written by scans, read by csr-era kernels, overwritten by GEMM4 at the end.
  char* sout = (char*)d_out;
  int*   torig = (int*)(sout + 0);                           // 32768 ints
  int*   cmap  = (int*)(sout + 131072);                      // 32768 ints
  float* confc = (float*)(sout + 262144);                    // 32768 f32
  int*   bsum  = (int*)(sout + 393216);                      // 32 ints
  int*   boff  = (int*)(sout + 393344);                      // 32 ints
  int*   minfo = (int*)(sout + 393472);                      // 2 ints

  // fused prologue: all weight transposes + input converts + mask sniff
  (void)hipMemsetAsync(u8flag, 0, sizeof(int), stream);
  prologue_k<<<12416, 256, 0, stream>>>(
      pred, obj, W1a, W1b, W2a, W2b,
      predb, objb, W1at, W1bt, W2at, W2bt,
      (const unsigned char*)mask, u8flag);

  // prep (+ fused scan1) -> scan2 -> scan3
  prep_k<<<32, 1024, 0, stream>>>(tt, pid, ptw, edges, mask, u8flag,
                                  conf, se, oe, bsum);
  scan2_k<<<1, 64, 0, stream>>>(bsum, boff, minfo);
  scan3_k<<<32, 1024, 0, stream>>>(se, boff, conf, torig, cmap, confc);

  // GEMM1: gather folded into staging; (32768x1536)@(1536x512) -> h  [256^2 phase]
  gemm8g_k<<<dim3(128, 2), 512, 0, stream>>>(objb, predb, edges, W1at, b1a, h);

  // wave-parallel CSR build (reuses W1at space — dead now)
  csr2_k<<<2048, 256, 0, stream>>>(se, oe, deg, slot);

  // GEMM2p (persistent, 2 m-tiles/block): h @ W1b_p -> relu*conf -> new_p
  gemm2p_k<<<dim3(64, 8), 256, 0, stream>>>(
      h, W1bt + 512 * 512, b1b + 512, conf, out + 4194304);

  // GEMM2so (persistent, 2 m-tiles/block): compacted rows -> new_s / new_o
  gemm2so_k<<<dim3(128, 8), 256, 0, stream>>>(
      h, torig, confc, W1bt, b1b, minfo, news, newo);

  // CSR pool -> pooled (bf16, 8192x512)
  pool2_k<<<Bc * Oc, 256, 0, stream>>>(news, newo, deg, slot, conf, cmap, pooled);

  // GEMM3: pooled @ W2a -> h2
  gemm_k<0><<<dim3(64, 4), 256, 0, stream>>>(
      pooled, W2at, b2a, h2, nullptr, 8192, 512, 512);

  // GEMM4: h2 @ W2b -> new_obj (f32, d_out) — overwrites compaction scratch
  gemm_k<2><<<dim3(64, 4), 256, 0, stream>>>(
      h2, W2bt, b2b, nullptr, out, 8192, 512, 512);
}

// Round 14
// 209.781 us; speedup vs baseline: 1.1366x; 1.1366x over previous
//
#include <hip/hip_runtime.h>
#include <hip/hip_bf16.h>
#include <cstdint>
#include <cstddef>

#define DEV __device__ __forceinline__

typedef __attribute__((ext_vector_type(8))) short  s8v;    // 8 bf16 (4 VGPR)
typedef __attribute__((ext_vector_type(4))) float  f4v;    // MFMA acc / 16B f32 load
typedef __attribute__((ext_vector_type(4))) uint32_t u4v;  // 16B packed store

// ---------- bf16 helpers ----------
DEV unsigned short f2bf(float x) {                 // RNE bithack (host-independent path)
  union { float f; uint32_t u; } v; v.f = x;
  uint32_t u = v.u + 0x7FFFu + ((v.u >> 16) & 1u);
  return (unsigned short)(u >> 16);
}
// HW packed convert: 2 f32 -> u32 of 2 bf16 (RNE, identical to f2bf)
DEV uint32_t cvtpk2(float lo, float hi) {
  uint32_t r;
  asm("v_cvt_pk_bf16_f32 %0, %1, %2" : "=v"(r) : "v"(lo), "v"(hi));
  return r;
}
DEV unsigned short f2bf_fast(float x) { return (unsigned short)cvtpk2(x, 0.f); }
DEV float bf2f(unsigned short b) {
  union { uint32_t u; float f; } v; v.u = ((uint32_t)b) << 16;
  return v.f;
}

// ---------- async global->LDS 16B (dest = wave-uniform base + lane*16) ----------
DEV void async_copy16(void* lds, const void* g) {
  typedef __attribute__((address_space(3))) uint32_t lds_t;
  typedef const __attribute__((address_space(1))) uint32_t g_t;
  __builtin_amdgcn_global_load_lds((g_t*)g, (lds_t*)lds, 16, 0, 0);
}

#define WAITV4()    asm volatile("s_waitcnt vmcnt(4)" ::: "memory")
#define WAITV0()    asm volatile("s_waitcnt vmcnt(0)" ::: "memory")
#define MEMFENCE()  asm volatile("" ::: "memory")

constexpr int Bc = 32, Oc = 256, Tc = 1024;
constexpr int BM = 128, BN = 128, BK = 64;         // 128^2 kernel tile
constexpr int CSR_CAP = 46;   // max degree per (b,o); P(exceed) ~ 1e-19

// bijective XCD chunk swizzle + n-inner decomposition.
DEV void swz_mn(int nyb, int* mb, int* nb) {
  const int nwg = gridDim.x * gridDim.y;            // multiple of 8 for all uses
  const int w   = blockIdx.x + blockIdx.y * gridDim.x;
  const int cpx = nwg >> 3;
  const int s   = (w & 7) * cpx + (w >> 3);
  *mb = s / nyb;
  *nb = s % nyb;
}

// ---------------------------------------------------------------------------
// prologue_k: ALL independent prologue work in ONE launch (was 7 dispatches;
// measured ~30us saved in round 10).  Block-range role dispatch:
//   [0,8192)      cvt pred  f32->bf16 (8 elem/thread)
//   [8192,10240)  cvt obj   f32->bf16
//   [10240,11008) tcvt W1a | [11008,11776) tcvt W1b
//   [11776,12032) tcvt W2a | [12032,12288) tcvt W2b
//   [12288,12416) detect: mask-dtype sniff (flag pre-zeroed by memset)
// ---------------------------------------------------------------------------
__global__ __launch_bounds__(256)
void prologue_k(const float* __restrict__ pred, const float* __restrict__ obj,
                const float* __restrict__ W1a, const float* __restrict__ W1b,
                const float* __restrict__ W2a, const float* __restrict__ W2b,
                unsigned short* __restrict__ predb, unsigned short* __restrict__ objb,
                unsigned short* __restrict__ W1at, unsigned short* __restrict__ W1bt,
                unsigned short* __restrict__ W2at, unsigned short* __restrict__ W2bt,
                const unsigned char* __restrict__ maskb, int* __restrict__ flag)
{
  __shared__ float tile[32][33];
  const int b = blockIdx.x;
  const int tid = threadIdx.x;

  if (b < 10240) {                                  // bulk f32->bf16 convert
    const float* in = (b < 8192) ? pred : obj;
    unsigned short* outp = (b < 8192) ? predb : objb;
    const int i = ((b < 8192) ? b : b - 8192) * 256 + tid;
    const f4v v0 = *(const f4v*)(in + (size_t)i * 8);
    const f4v v1 = *(const f4v*)(in + (size_t)i * 8 + 4);
    u4v pk;
    pk.x = cvtpk2(v0.x, v0.y);
    pk.y = cvtpk2(v0.z, v0.w);
    pk.z = cvtpk2(v1.x, v1.y);
    pk.w = cvtpk2(v1.z, v1.w);
    *(u4v*)(outp + (size_t)i * 8) = pk;
  } else if (b < 12288) {                           // weight transpose+convert
    const float* W; unsigned short* Wt; int K, N, kb, nb;
    if (b < 11008)      { W = W1a; Wt = W1at; K = 1536; N = 512;
                          const int r = b - 10240; kb = r % 48; nb = r / 48; }
    else if (b < 11776) { W = W1b; Wt = W1bt; K = 512;  N = 1536;
                          const int r = b - 11008; kb = r % 16; nb = r / 16; }
    else if (b < 12032) { W = W2a; Wt = W2at; K = 512;  N = 512;
                          const int r = b - 11776; kb = r % 16; nb = r / 16; }
    else                { W = W2b; Wt = W2bt; K = 512;  N = 512;
                          const int r = b - 12032; kb = r % 16; nb = r / 16; }
    const int k0 = kb * 32, n0 = nb * 32;
    const int tx = tid & 31, ty = tid >> 5;
    #pragma unroll
    for (int i = 0; i < 32; i += 8)
      tile[ty + i][tx] = W[(size_t)(k0 + ty + i) * N + (n0 + tx)];
    __syncthreads();
    #pragma unroll
    for (int i = 0; i < 32; i += 8)
      Wt[(size_t)(n0 + ty + i) * K + (k0 + tx)] = f2bf(tile[tx][ty + i]);
  } else {                                          // detect (parallel)
    const int i = (b - 12288) * 256 + tid;          // covers 32768 bytes
    const int local = ((i & 3) && maskb[i]) ? 1 : 0;
    const unsigned long long bal = __ballot(local);
    if (bal != 0 && (tid & 63) == 0) atomicOr(flag, 1);
  }
}

// ---------------------------------------------------------------------------
// 256x256 8-wave phase-interleaved K-loop with fragment-register reuse.
// (GEMM1 only — measured best: 68.5us vs 77us factored, vs ~87us 128^2.)
// ---------------------------------------------------------------------------
#define READ_A(QM, DST) do {                                                    \
    _Pragma("unroll")                                                           \
    for (int i = 0; i < 4; ++i) {                                               \
      const int row = wm * 128 + ((QM) * 4 + i) * 16 + (lane & 15);             \
      _Pragma("unroll")                                                         \
      for (int kk = 0; kk < 2; ++kk) {                                          \
        const int c = kk * 4 + (lane >> 4);                                     \
        DST[i][kk] = *(const s8v*)(Ab_ + row * 128 + ((c ^ (row & 7)) << 4));   \
      }                                                                         \
    }                                                                           \
  } while (0)

#define READ_B(QN, DST) do {                                                    \
    _Pragma("unroll")                                                           \
    for (int j = 0; j < 2; ++j) {                                               \
      const int row = wn * 64 + ((QN) * 2 + j) * 16 + (lane & 15);              \
      _Pragma("unroll")                                                         \
      for (int kk = 0; kk < 2; ++kk) {                                          \
        const int c = kk * 4 + (lane >> 4);                                     \
        DST[j][kk] = *(const s8v*)(Bb_ + row * 128 + ((c ^ (row & 7)) << 4));   \
      }                                                                         \
    }                                                                           \
  } while (0)

#define SYNC_MFMA(QM, QN, AF, BF) do {                                          \
    MEMFENCE();                                                                 \
    __builtin_amdgcn_s_barrier();                                               \
    asm volatile("s_waitcnt lgkmcnt(0)" ::: "memory");                          \
    __builtin_amdgcn_sched_barrier(0);                                          \
    __builtin_amdgcn_s_setprio(1);                                              \
    _Pragma("unroll")                                                           \
    for (int i = 0; i < 4; ++i)                                                 \
      _Pragma("unroll")                                                         \
      for (int j = 0; j < 2; ++j)                                               \
        _Pragma("unroll")                                                       \
        for (int kk = 0; kk < 2; ++kk)                                          \
          acc[(QM) * 4 + i][(QN) * 2 + j] =                                     \
            __builtin_amdgcn_mfma_f32_16x16x32_bf16(                            \
              AF[i][kk], BF[j][kk], acc[(QM) * 4 + i][(QN) * 2 + j], 0, 0, 0);  \
    __builtin_amdgcn_s_setprio(0);                                              \
  } while (0)

#define ENDPHASE() do { MEMFENCE(); __builtin_amdgcn_s_barrier(); } while (0)

#define KTILE_BODY() do {                                                       \
    const int par = t & 1, px = par ^ 1;                                        \
    const char* Ab_ = smem + par * 65536;                                       \
    const char* Bb_ = Ab_ + 32768;                                              \
    const bool s1 = (t + 1 < nk), s2 = (t + 2 < nk);                            \
    /* P0 */                                                                    \
    READ_A(0, af); READ_B(0, bf0);                                              \
    if (s1) stageA(px, 1, t + 1);                                               \
    SYNC_MFMA(0, 0, af, bf0);                                                   \
    ENDPHASE();                                                                 \
    /* P1 */                                                                    \
    READ_B(1, bf1);                                                             \
    if (s1) stageB(px, 1, t + 1);                                               \
    SYNC_MFMA(0, 1, af, bf1);                                                   \
    ENDPHASE();                                                                 \
    /* P2 */                                                                    \
    READ_A(1, af);                                                              \
    if (s2) stageA(par, 0, t + 2);                                              \
    SYNC_MFMA(1, 1, af, bf1);                                                   \
    ENDPHASE();                                                                 \
    /* P3 */                                                                    \
    if (s2) stageB(par, 0, t + 2);                                              \
    SYNC_MFMA(1, 0, af, bf0);                                                   \
    if (s2) { WAITV4(); } else if (s1) { WAITV0(); }                            \
    ENDPHASE();                                                                 \
  } while (0)

// ---------------------------------------------------------------------------
// Gathered-A 256^2 GEMM (GEMM1): A row m = [objb[s(m)], predb[m], objb[o(m)]]
// M=32768 N=512 K=1536.
// ---------------------------------------------------------------------------
__global__ __launch_bounds__(512, 2)
void gemm8g_k(const unsigned short* __restrict__ objb,
              const unsigned short* __restrict__ predb,
              const int* __restrict__ edges,
              const unsigned short* __restrict__ Bt,   // (512,1536) bf16
              const float* __restrict__ bias,
              unsigned short* __restrict__ outp)       // (32768,512) bf16
{
  __shared__ __align__(16) char smem[131072];

  const int tid = threadIdx.x, lane = tid & 63, wave = tid >> 6;
  const int wm = wave >> 2, wn = wave & 3;
  int mb, nb; swz_mn(gridDim.y, &mb, &nb);
  const int m0 = mb * 256, n0 = nb * 256;
  const int rl  = tid >> 3;
  const int cs8 = ((lane & 7) ^ (lane >> 3)) * 8;
  const int rB0 = (rl >> 5) * 64 + (rl & 31);

  // 12 per-thread gathered byte offsets; c2 = s*2+qm -> row = s*128+qm*64+rl
  uint32_t offS[4], offP[4], offO[4];
  #pragma unroll
  for (int c2 = 0; c2 < 4; ++c2) {
    const int r = (c2 >> 1) * 128 + (c2 & 1) * 64 + rl;
    const int m = m0 + r;
    const int ob = (m >> 10) * Oc;
    offS[c2] = (uint32_t)((ob + edges[2 * m])     * 1024 + cs8 * 2);
    offO[c2] = (uint32_t)((ob + edges[2 * m + 1]) * 1024 + cs8 * 2);
    offP[c2] = (uint32_t)(m * 1024 + cs8 * 2);
  }
  const unsigned short* srcB = Bt + (size_t)(n0 + rB0) * 1536 + cs8;

  auto stageA = [&](int p, int qm, int kt) {
    const int reg = kt >> 3;
    const uint32_t koff = (uint32_t)(kt & 7) * 128u;
    #pragma unroll
    for (int s = 0; s < 2; ++s) {
      const int c2 = s * 2 + qm;
      const char* src;
      if (reg == 0)      src = (const char*)objb  + offS[c2] + koff;
      else if (reg == 1) src = (const char*)predb + offP[c2] + koff;
      else               src = (const char*)objb  + offO[c2] + koff;
      async_copy16(smem + p * 65536 + ((s * 128 + qm * 64 + wave * 8) << 7), src);
    }
  };
  auto stageB = [&](int p, int qn, int kt) {
    #pragma unroll
    for (int s = 0; s < 2; ++s)
      async_copy16(smem + p * 65536 + 32768 +
                     ((s * 128 + qn * 32 + (wave >> 2) * 64 + (wave & 3) * 8) << 7),
                   srcB + (size_t)(s * 128 + qn * 32) * 1536 + kt * 64);
  };

  f4v acc[8][4] = {};
  s8v af[4][2], bf0[2][2], bf1[2][2];
  constexpr int nk = 24;

  stageA(0, 0, 0); stageB(0, 0, 0); stageA(0, 1, 0); stageB(0, 1, 0);
  stageA(1, 0, 1); stageB(1, 0, 1);
  WAITV4();
  MEMFENCE();
  __builtin_amdgcn_s_barrier();

  for (int t = 0; t < nk; ++t) KTILE_BODY();

  const int cn = lane & 15, rq4 = (lane >> 4) * 4;
  #pragma unroll
  for (int f = 0; f < 8; ++f) {
    const int gr0 = m0 + wm * 128 + f * 16 + rq4;
    #pragma unroll
    for (int g = 0; g < 4; ++g) {
      const int gc = n0 + wn * 64 + g * 16 + cn;
      const float bv = bias[gc];
      #pragma unroll
      for (int r = 0; r < 4; ++r) {
        float val = acc[f][g][r] + bv;
        val = val > 0.f ? val : 0.f;
        outp[(size_t)(gr0 + r) * 512 + gc] = f2bf_fast(val);
      }
    }
  }
}

// ---------------------------------------------------------------------------
// Generic 128x128 bf16 GEMM (single-buffer).
// EPI: 0 = relu->bf16 (stride N); 2 = relu->f32; 3 = relu*conf->f32
// ---------------------------------------------------------------------------
template<int EPI>
__global__ __launch_bounds__(256)
void gemm_k(const unsigned short* __restrict__ Abf,
            const unsigned short* __restrict__ Bt,
            const float* __restrict__ bias,
            const float* __restrict__ conf,
            unsigned short* __restrict__ out_bf,
            float* __restrict__ out_f32,
            int M, int N, int K)
{
  __shared__ __align__(16) char smem[BM * BK * 2 + BN * BK * 2];
  char* As = smem;
  char* Bs = smem + BM * BK * 2;

  const int tid  = threadIdx.x;
  const int lane = tid & 63;
  const int wave = tid >> 6;
  const int wm = wave >> 1, wn = wave & 1;
  int mb, nb; swz_mn(gridDim.y, &mb, &nb);
  const int m0 = mb * BM;
  const int n0 = nb * BN;

  f4v acc[4][4] = {};

  for (int k0 = 0; k0 < K; k0 += BK) {
    {
      const int r8 = lane >> 3;
      const int cs = (lane & 7) ^ r8;
      const unsigned short* src = Bt + (size_t)(n0 + wave * 32 + r8) * K + k0 + cs * 8;
      #pragma unroll
      for (int i = 0; i < 4; ++i)
        async_copy16(Bs + (wave * 32 + i * 8) * 128, src + (size_t)i * 8 * K);
      const unsigned short* srca = Abf + (size_t)(m0 + wave * 32 + r8) * K + k0 + cs * 8;
      #pragma unroll
      for (int i = 0; i < 4; ++i)
        async_copy16(As + (wave * 32 + i * 8) * 128, srca + (size_t)i * 8 * K);
    }
    __syncthreads();

    #pragma unroll
    for (int kk = 0; kk < 2; ++kk) {
      s8v af[4], bfv[4];
      #pragma unroll
      for (int i = 0; i < 4; ++i) {
        const int row = wm * 64 + i * 16 + (lane & 15);
        const int c = kk * 4 + (lane >> 4);
        af[i] = *(const s8v*)(As + row * 128 + ((c ^ (row & 7)) << 4));
      }
      #pragma unroll
      for (int j = 0; j < 4; ++j) {
        const int row = wn * 64 + j * 16 + (lane & 15);
        const int c = kk * 4 + (lane >> 4);
        bfv[j] = *(const s8v*)(Bs + row * 128 + ((c ^ (row & 7)) << 4));
      }
      #pragma unroll
      for (int i = 0; i < 4; ++i)
        #pragma unroll
        for (int j = 0; j < 4; ++j)
          acc[i][j] = __builtin_amdgcn_mfma_f32_16x16x32_bf16(af[i], bfv[j], acc[i][j], 0, 0, 0);
    }
    __syncthreads();
  }

  const int cn = lane & 15, rq4 = (lane >> 4) * 4;
  #pragma unroll
  for (int i = 0; i < 4; ++i) {
    const int gr0 = m0 + wm * 64 + i * 16 + rq4;
    #pragma unroll
    for (int j = 0; j < 4; ++j) {
      const int gc = n0 + wn * 64 + j * 16 + cn;
      const float bv = bias[gc];
      #pragma unroll
      for (int r = 0; r < 4; ++r) {
        float val = acc[i][j][r] + bv;
        val = val > 0.f ? val : 0.f;
        const int gr = gr0 + r;
        if (EPI == 0) out_bf[(size_t)gr * N + gc] = f2bf_fast(val);
        else if (EPI == 2) out_f32[(size_t)gr * N + gc] = val;
        else { out_f32[(size_t)gr * N + gc] = val * conf[gr]; }
      }
    }
  }
}

// ---------------------------------------------------------------------------
// GEMM2so: gathered-A 128^2 GEMM over COMPACTED masked rows.
// Block mapping is ACTIVE-COUNT-aware: bijective XCD swizzle over the
// nact = (Mp/128)*8 live blocks so they spread across all 8 XCDs.
// ---------------------------------------------------------------------------
__global__ __launch_bounds__(256)
void gemm2so_k(const unsigned short* __restrict__ h,
               const int* __restrict__ torig,
               const float* __restrict__ confc,
               const unsigned short* __restrict__ W1bt,   // (1536,512) bf16
               const float* __restrict__ b1b,
               const int* __restrict__ minfo,             // [0]=M', [1]=Mpad
               unsigned short* __restrict__ news_c,
               unsigned short* __restrict__ newo_c)
{
  const int Mp   = minfo[1];
  const int nact = (Mp >> 7) << 3;               // live blocks, multiple of 8
  const int w    = blockIdx.x + blockIdx.y * gridDim.x;
  if (w >= nact) return;                         // uniform exit, pre-barrier
  const int cpx = nact >> 3;
  const int s   = (w & 7) * cpx + (w >> 3);      // bijective over [0,nact)
  const int mb  = s >> 3, nb = s & 7;            // n-inner
  const int m0  = mb * BM;
  const int Mr  = minfo[0];                      // > 0 here

  __shared__ __align__(16) char smem[BM * BK * 2 + BN * BK * 2];
  char* As = smem;
  char* Bs = smem + BM * BK * 2;

  const int tid  = threadIdx.x;
  const int lane = tid & 63;
  const int wave = tid >> 6;
  const int wm = wave >> 1, wn = wave & 1;
  const int n0 = nb * BN;                        // 0..1023 logical so-col
  const int r8 = lane >> 3;
  const int cs8 = ((lane & 7) ^ r8) * 8;

  // gathered per-lane A row pointers (4 rows: wave*32 + i*8 + r8)
  const unsigned short* aP[4];
  #pragma unroll
  for (int i = 0; i < 4; ++i) {
    int m = m0 + wave * 32 + i * 8 + r8;
    m = m < Mr ? m : Mr - 1;
    aP[i] = h + (size_t)torig[m] * 512 + cs8;
  }
  const int nrow0 = (nb < 4) ? n0 : n0 + 512;    // skip p-rows of W1bt
  const unsigned short* bsrc = W1bt + (size_t)(nrow0 + wave * 32 + r8) * 512 + cs8;

  f4v acc[4][4] = {};

  for (int kt = 0; kt < 8; ++kt) {
    const int kin = kt * 64;
    #pragma unroll
    for (int i = 0; i < 4; ++i)
      async_copy16(Bs + (wave * 32 + i * 8) * 128, bsrc + (size_t)(i * 8) * 512 + kin);
    #pragma unroll
    for (int i = 0; i < 4; ++i)
      async_copy16(As + (wave * 32 + i * 8) * 128, aP[i] + kin);
    __syncthreads();

    #pragma unroll
    for (int kk = 0; kk < 2; ++kk) {
      s8v af[4], bfv[4];
      #pragma unroll
      for (int i = 0; i < 4; ++i) {
        const int row = wm * 64 + i * 16 + (lane & 15);
        const int c = kk * 4 + (lane >> 4);
        af[i] = *(const s8v*)(As + row * 128 + ((c ^ (row & 7)) << 4));
      }
      #pragma unroll
      for (int j = 0; j < 4; ++j) {
        const int row = wn * 64 + j * 16 + (lane & 15);
        const int c = kk * 4 + (lane >> 4);
        bfv[j] = *(const s8v*)(Bs + row * 128 + ((c ^ (row & 7)) << 4));
      }
      #pragma unroll
      for (int i = 0; i < 4; ++i)
        #pragma unroll
        for (int j = 0; j < 4; ++j)
          acc[i][j] = __builtin_amdgcn_mfma_f32_16x16x32_bf16(af[i], bfv[j], acc[i][j], 0, 0, 0);
    }
    __syncthreads();
  }

  const float* bb = b1b + ((nb < 4) ? n0 : 512 + n0);   // b1b index: s:0..511, o:1024..1535
  unsigned short* outp = (nb < 4) ? news_c : newo_c;
  const int c0 = (nb & 3) * 128;
  const int cn = lane & 15, rq4 = (lane >> 4) * 4;
  #pragma unroll
  for (int i = 0; i < 4; ++i) {
    const int gr0 = m0 + wm * 64 + i * 16 + rq4;
    #pragma unroll
    for (int j = 0; j < 4; ++j) {
      const int lc = wn * 64 + j * 16 + cn;
      const float bv = bb[lc];
      #pragma unroll
      for (int r = 0; r < 4; ++r) {
        const int gr = gr0 + r;
        float val = acc[i][j][r] + bv;
        val = val > 0.f ? val : 0.f;
        val *= confc[gr < Mr ? gr : 0];
        if (gr < Mr) outp[(size_t)gr * 512 + c0 + lc] = f2bf_fast(val);
      }
    }
  }
}

// ---------------------------------------------------------------------------
// prep (+ fused scan1): 32 blocks x 1024. Computes conf/se/oe AND per-block
// masked-count bsum (the ballot is needed anyway).
// ---------------------------------------------------------------------------
__global__ __launch_bounds__(1024)
void prep_k(const int* __restrict__ tt, const int* __restrict__ pid,
            const float* __restrict__ ptw, const int* __restrict__ edges,
            const void* __restrict__ mask, const int* __restrict__ u8flag,
            float* __restrict__ conf, int* __restrict__ se,
            int* __restrict__ oe, int* __restrict__ bsum)
{
  const int m = blockIdx.x * 1024 + threadIdx.x;
  const int t = tt[m];
  float c = 0.f;
  if (t == 0) c = 1.f;
  else if (t == 1) c = 1.f / (1.f + expf(-ptw[pid[m]]));
  conf[m] = c;
  bool mk;
  if (*u8flag) mk = ((const unsigned char*)mask)[m] != 0;
  else         mk = ((const int*)mask)[m] != 0;
  se[m] = mk ? edges[2 * m]     : -1;
  oe[m] = mk ? edges[2 * m + 1] : -1;

  const unsigned long long bal = __ballot(mk);
  __shared__ int wc[16];
  if ((threadIdx.x & 63) == 0) wc[threadIdx.x >> 6] = (int)__popcll(bal);
  __syncthreads();
  if (threadIdx.x == 0) {
    int ssum = 0;
    #pragma unroll
    for (int i = 0; i < 16; ++i) ssum += wc[i];
    bsum[blockIdx.x] = ssum;
  }
}

__global__ void scan2_k(const int* __restrict__ bsum, int* __restrict__ boff,
                        int* __restrict__ minfo)
{
  if (threadIdx.x == 0) {
    int s = 0;
    for (int i = 0; i < 32; ++i) { boff[i] = s; s += bsum[i]; }
    minfo[0] = s;
    minfo[1] = (s + 127) & ~127;
  }
}

__global__ __launch_bounds__(1024)
void scan3_k(const int* __restrict__ se, const int* __restrict__ boff,
             const float* __restrict__ conf,
             int* __restrict__ torig, int* __restrict__ cmap,
             float* __restrict__ confc)
{
  const int m = blockIdx.x * 1024 + threadIdx.x;
  const int lane = threadIdx.x & 63, w = threadIdx.x >> 6;
  const bool mv = se[m] >= 0;
  const unsigned long long bal = __ballot(mv);
  __shared__ int wc[16];
  if (lane == 0) wc[w] = (int)__popcll(bal);
  __syncthreads();
  int woff = 0;
  for (int i = 0; i < w; ++i) woff += wc[i];
  if (mv) {
    const int c = boff[blockIdx.x] + woff +
                  (int)__popcll(bal & ((1ull << lane) - 1ull));
    torig[c] = m;
    cmap[m]  = c;
    confc[c] = conf[m];
  }
}

// ---------------------------------------------------------------------------
// Wave-parallel CSR build: one wave per (b,o). Deterministic via ballot rank.
// ---------------------------------------------------------------------------
__global__ __launch_bounds__(256)
void csr2_k(const int* __restrict__ se, const int* __restrict__ oe,
            int* __restrict__ deg, int* __restrict__ slot)
{
  const int wid  = blockIdx.x * 4 + (threadIdx.x >> 6);  // (b<<8)|u
  const int b    = wid >> 8;
  const int u    = wid & 255;
  const int lane = threadIdx.x & 63;
  const int mb   = b * Tc;
  int* sl = slot + (size_t)wid * CSR_CAP;
  const unsigned long long lt = (1ull << lane) - 1ull;
  int cnt = 0;
  #pragma unroll 4
  for (int c = 0; c < 16; ++c) {
    const int t = c * 64 + lane;
    const int s = se[mb + t];
    const int o = oe[mb + t];
    const unsigned long long ms = __ballot(s == u);
    const unsigned long long mo = __ballot(o == u);
    if (s == u) {
      const int pos = cnt + (int)__popcll(ms & lt);
      if (pos < CSR_CAP) sl[pos] = 2 * t;
    }
    cnt += (int)__popcll(ms);
    if (o == u) {
      const int pos = cnt + (int)__popcll(mo & lt);
      if (pos < CSR_CAP) sl[pos] = 2 * t + 1;
    }
    cnt += (int)__popcll(mo);
  }
  if (lane == 0) deg[wid] = cnt < CSR_CAP ? cnt : CSR_CAP;
}

// ---------------------------------------------------------------------------
// CSR pool over COMPACTED rows: row index = cmap[b*Tc + t].
// ---------------------------------------------------------------------------
__global__ __launch_bounds__(256)
void pool2_k(const unsigned short* __restrict__ S, const unsigned short* __restrict__ Ov,
             const int* __restrict__ deg, const int* __restrict__ slot,
             const float* __restrict__ conf, const int* __restrict__ cmap,
             unsigned short* __restrict__ pooled)
{
  const int bo = blockIdx.x;            // b*256 + o
  const int b  = bo >> 8;
  const int u  = threadIdx.x;
  const int d  = deg[bo];
  const int* sl = slot + (size_t)bo * CSR_CAP;
  float a0 = 0.f, a1 = 0.f, w = 0.f;
  for (int i = 0; i < d; ++i) {
    const int e = sl[i];                // uniform load
    const int t = e >> 1;
    const int c = cmap[b * Tc + t];     // valid: slots contain masked t only
    const unsigned short* row = ((e & 1) ? Ov : S) + (size_t)c * 512;
    const uint32_t pr = *(const uint32_t*)(row + 2 * u);
    a0 += bf2f((unsigned short)pr);
    a1 += bf2f((unsigned short)(pr >> 16));
    w  += conf[b * Tc + t];
  }
  const float denom = (w > 0.f) ? w : 1.f;
  const size_t ob = (size_t)bo * 512;
  *(uint32_t*)(pooled + ob + 2 * u) = cvtpk2(a0 / denom, a1 / denom);
}

// ---------------------------------------------------------------------------
extern "C" void kernel_launch(void* const* d_in, const int* in_sizes, int n_in,
                              void* d_out, int out_size, void* d_ws, size_t ws_size,
                              hipStream_t stream)
{
  const float* obj  = (const float*)d_in[0];
  const float* pred = (const float*)d_in[1];
  const float* W1a  = (const float*)d_in[2];
  const float* b1a  = (const float*)d_in[3];
  const float* W1b  = (const float*)d_in[4];
  const float* b1b  = (const float*)d_in[5];
  const float* W2a  = (const float*)d_in[6];
  const float* b2a  = (const float*)d_in[7];
  const float* W2b  = (const float*)d_in[8];
  const float* b2b  = (const float*)d_in[9];
  const float* ptw  = (const float*)d_in[10];
  const int*   edges = (const int*)d_in[11];
  const void*  mask  = d_in[12];
  const int*   tt    = (const int*)d_in[13];
  const int*   pid   = (const int*)d_in[14];
  float* out = (float*)d_out;

  char* ws = (char*)d_ws;
  // [0, 4194304): transposed bf16 weights.
  // W1at [0, 1572864) is DEAD after gemm1 -> reused for CSR deg+slot.
  unsigned short* W1at = (unsigned short*)(ws + 0);          // 512x1536
  unsigned short* W1bt = (unsigned short*)(ws + 1572864);    // 1536x512
  unsigned short* W2at = (unsigned short*)(ws + 3145728);    // 512x512
  unsigned short* W2bt = (unsigned short*)(ws + 3670016);    // 512x512
  int* deg  = (int*)(ws + 0);                                // 8192 ints
  int* slot = (int*)(ws + 32768);                            // 8192*46 ints
  unsigned short* h    = (unsigned short*)(ws + 4194304);    // 32768x512 bf16, 32MB
  unsigned short* pooled = h;                                // 8192x512 (post-GEMM2)
  unsigned short* h2   = (unsigned short*)(ws + 12582912);   // 8192x512 bf16 (GEMM3 out)
  unsigned short* news = (unsigned short*)(ws + 37748736);   // 32768x512 bf16 (compacted)
  unsigned short* newo = (unsigned short*)(ws + 71303168);   // 32768x512 bf16 (compacted)
  unsigned short* objb = news;                               // 32x256x512 (pre-GEMM1)
  unsigned short* predb = (unsigned short*)(ws + 46137344);  // 32x1024x512
  float* conf = (float*)(ws + 104857600);
  int*   se   = (int*)(ws + 104988672);
  int*   oe   = (int*)(ws + 105119744);
  int* u8flag = (int*)(ws + 105250816);

  // Compaction scratch lives in d_out's new_obj region [0, 400KB):
  // written by scans, read by csr-era kernels, overwritten by GEMM4 at the end.
  char* sout = (char*)d_out;
  int*   torig = (int*)(sout + 0);                           // 32768 ints
  int*   cmap  = (int*)(sout + 131072);                      // 32768 ints
  float* confc = (float*)(sout + 262144);                    // 32768 f32
  int*   bsum  = (int*)(sout + 393216);                      // 32 ints
  int*   boff  = (int*)(sout + 393344);                      // 32 ints
  int*   minfo = (int*)(sout + 393472);                      // 2 ints

  // fused prologue: all weight transposes + input converts + mask sniff
  (void)hipMemsetAsync(u8flag, 0, sizeof(int), stream);
  prologue_k<<<12416, 256, 0, stream>>>(
      pred, obj, W1a, W1b, W2a, W2b,
      predb, objb, W1at, W1bt, W2at, W2bt,
      (const unsigned char*)mask, u8flag);

  // prep (+ fused scan1) -> scan2 -> scan3
  prep_k<<<32, 1024, 0, stream>>>(tt, pid, ptw, edges, mask, u8flag,
                                  conf, se, oe, bsum);
  scan2_k<<<1, 64, 0, stream>>>(bsum, boff, minfo);
  scan3_k<<<32, 1024, 0, stream>>>(se, boff, conf, torig, cmap, confc);

  // GEMM1: gather folded into staging; (32768x1536)@(1536x512) -> h  [256^2 phase]
  gemm8g_k<<<dim3(128, 2), 512, 0, stream>>>(objb, predb, edges, W1at, b1a, h);

  // wave-parallel CSR build (reuses W1at space — dead now)
  csr2_k<<<2048, 256, 0, stream>>>(se, oe, deg, slot);

  // GEMM2p: h @ W1b[:,512:1024] -> relu*conf -> new_p (f32, d_out) for ALL rows
  gemm_k<3><<<dim3(256, 4), 256, 0, stream>>>(
      h, W1bt + 512 * 512, b1b + 512, conf, nullptr, out + 4194304, 32768, 512, 512);

  // GEMM2so: compacted masked rows -> new_s / new_o (bf16, compacted)
  gemm2so_k<<<dim3(256, 8), 256, 0, stream>>>(
      h, torig, confc, W1bt, b1b, minfo, news, newo);

  // CSR pool -> pooled (bf16, 8192x512)
  pool2_k<<<Bc * Oc, 256, 0, stream>>>(news, newo, deg, slot, conf, cmap, pooled);

  // GEMM3: pooled @ W2a -> h2
  gemm_k<0><<<dim3(64, 4), 256, 0, stream>>>(
      pooled, W2at, b2a, nullptr, h2, nullptr, 8192, 512, 512);

  // GEMM4: h2 @ W2b -> new_obj (f32, d_out) — overwrites compaction scratch
  gemm_k<2><<<dim3(64, 4), 256, 0, stream>>>(
      h2, W2bt, b2b, nullptr, nullptr, out, 8192, 512, 512);
}